// Round 4
// baseline (5125.240 us; speedup 1.0000x reference)
//
#include <hip/hip_runtime.h>
#include <math.h>

#define H 51
#define TSEEN 256
#define FUT 16
#define TTOT (TSEEN + FUT)
#define NB 4                   // batches per block
#define THREADS 256            // 4 waves; thread = (k-quarter q, unit u)
#define NBLOCKS (2048 / NB)    // 512 blocks -> 2 blocks/CU

typedef float v2f __attribute__((ext_vector_type(2)));

__device__ __forceinline__ float fast_rcp(float x) { return __builtin_amdgcn_rcpf(x); }

__device__ __forceinline__ float fast_sig(float x) {
  float e = __expf(-x);
  return fast_rcp(1.f + e);           // rcp(inf)=0 -> saturates cleanly
}

__device__ __forceinline__ float fast_tanh(float x) {
  float e = __expf(-2.f * fabsf(x));  // e in (0,1] -> overflow-safe
  return copysignf((1.f - e) * fast_rcp(1.f + e), x);
}

template<int C>
__device__ __forceinline__ float dppf(float v) {
  return __int_as_float(__builtin_amdgcn_mov_dpp(__float_as_int(v), C, 0xf, 0xf, true));
}
template<int C>
__device__ __forceinline__ v2f qswap(v2f v) {
  v2f r; r.x = dppf<C>(v.x); r.y = dppf<C>(v.y); return r;
}
// quad all-reduce: 0xB1 = quad_perm[1,0,3,2] (xor1), 0x4E = [2,3,0,1] (xor2)
#define QRED(X) do { X = X + qswap<0xB1>(X); X = X + qswap<0x4E>(X); } while (0)

__device__ __forceinline__ float pick(int q, v2f a, v2f b) {
  v2f s = (q & 2) ? b : a;
  return (q & 1) ? s.y : s.x;
}

__device__ __forceinline__ float ldw(const float* s, int rr, int kb, int j) {
  int k = kb + j;
  return (k < H) ? s[rr * H + k] : 0.f;
}

__device__ __forceinline__ void cell(float t0, float t1, float t2, float t3,
                                     float& c, float& h) {
  float iv = fast_sig(t0), fv = fast_sig(t1);
  float gv = fast_tanh(t2), ov = fast_sig(t3);
  c = fmaf(fv, c, iv * gv);
  h = ov * fast_tanh(c);
}

// 13 named weight registers per (matrix, gate-row) — no allocas, no spill.
#define DECLROW(p) float p##0,p##1,p##2,p##3,p##4,p##5,p##6,p##7,p##8,p##9,p##10,p##11,p##12
#define LOADROW(p, s, rr) do { \
  p##0=ldw(s,rr,kb,0);  p##1=ldw(s,rr,kb,1);  p##2=ldw(s,rr,kb,2);  p##3=ldw(s,rr,kb,3); \
  p##4=ldw(s,rr,kb,4);  p##5=ldw(s,rr,kb,5);  p##6=ldw(s,rr,kb,6);  p##7=ldw(s,rr,kb,7); \
  p##8=ldw(s,rr,kb,8);  p##9=ldw(s,rr,kb,9);  p##10=ldw(s,rr,kb,10); p##11=ldw(s,rr,kb,11); \
  p##12=ldw(s,rr,kb,12); } while (0)

#define PKF(w, h, a) __builtin_elementwise_fma((v2f){(w),(w)}, (h), (a))

#define L1J(j) { float4 hv = hp1[j]; \
  v2f lo = {hv.x, hv.y}; v2f hi = {hv.z, hv.w}; \
  A0 = PKF(w1a##j, lo, A0); B0 = PKF(w1a##j, hi, B0); \
  A1 = PKF(w1b##j, lo, A1); B1 = PKF(w1b##j, hi, B1); \
  A2 = PKF(w1c##j, lo, A2); B2 = PKF(w1c##j, hi, B2); \
  A3 = PKF(w1d##j, lo, A3); B3 = PKF(w1d##j, hi, B3); }

#define L2J(j) { float4 ha = hp2a[j]; float4 hb = hp2b[j]; \
  v2f alo = {ha.x, ha.y}; v2f ahi = {ha.z, ha.w}; \
  v2f blo = {hb.x, hb.y}; v2f bhi = {hb.z, hb.w}; \
  A0 = PKF(w2a##j, alo, A0); B0 = PKF(w2a##j, ahi, B0); \
  A0 = PKF(w3a##j, blo, A0); B0 = PKF(w3a##j, bhi, B0); \
  A1 = PKF(w2b##j, alo, A1); B1 = PKF(w2b##j, ahi, B1); \
  A1 = PKF(w3b##j, blo, A1); B1 = PKF(w3b##j, bhi, B1); \
  A2 = PKF(w2c##j, alo, A2); B2 = PKF(w2c##j, ahi, B2); \
  A2 = PKF(w3c##j, blo, A2); B2 = PKF(w3c##j, bhi, B2); \
  A3 = PKF(w2d##j, alo, A3); B3 = PKF(w2d##j, ahi, B3); \
  A3 = PKF(w3d##j, blo, A3); B3 = PKF(w3d##j, bhi, B3); }

#define CALL13(M) M(0) M(1) M(2) M(3) M(4) M(5) M(6) M(7) M(8) M(9) M(10) M(11) M(12)

__launch_bounds__(THREADS, 2)
__global__ void lstm2_kernel(const float* __restrict__ inp,
                             const float* __restrict__ Wih1,
                             const float* __restrict__ bih1,
                             const float* __restrict__ Whh1,
                             const float* __restrict__ bhh1,
                             const float* __restrict__ Wih2,
                             const float* __restrict__ bih2,
                             const float* __restrict__ Whh2,
                             const float* __restrict__ bhh2,
                             const float* __restrict__ Wlin,
                             const float* __restrict__ blin,
                             float* __restrict__ out)
{
  __shared__ __align__(16) float h1s[2][H + 1][NB];   // row H stays 0 (k-pad)
  __shared__ __align__(16) float h2s[2][H + 1][NB];
  __shared__ __align__(16) float xs[TSEEN][NB];
  __shared__ __align__(16) float parts[2][4][NB];     // [parity][wave][batch]

  const int tid  = threadIdx.x;
  const int wv   = tid >> 6;
  const int lane = tid & 63;
  const int q    = lane & 3;         // k-quarter for dots; batch for cell update
  const int ul   = lane >> 2;
  const int u    = wv * 16 + ul;     // unit 0..63 (51 active)
  const bool on  = (u < H);
  const int uc   = on ? u : (H - 1);
  const int kb   = 13 * q;           // k range [kb, kb+13), pad col 51 -> 0
  const int baseb = blockIdx.x * NB;

  // ---- zero LDS state ----
  for (int i = tid; i < 2 * (H + 1) * NB; i += THREADS) {
    (&h1s[0][0][0])[i] = 0.f;
    (&h2s[0][0][0])[i] = 0.f;
  }
  if (tid < 2 * 4 * NB) (&parts[0][0][0])[tid] = 0.f;

  // ---- stage inputs (coalesced over t) ----
  for (int i = tid; i < NB * TSEEN; i += THREADS) {
    int b = i >> 8, t = i & 255;
    xs[t][b] = inp[(size_t)(baseb + b) * TSEEN + t];
  }

  // ---- register-resident weights: 4 gate rows x k-quarter, all 3 matrices ----
  DECLROW(w1a); DECLROW(w1b); DECLROW(w1c); DECLROW(w1d);
  DECLROW(w2a); DECLROW(w2b); DECLROW(w2c); DECLROW(w2d);
  DECLROW(w3a); DECLROW(w3b); DECLROW(w3c); DECLROW(w3d);
  const int r0 = 0 * H + uc, r1 = 1 * H + uc, r2 = 2 * H + uc, r3 = 3 * H + uc;
  LOADROW(w1a, Whh1, r0); LOADROW(w1b, Whh1, r1); LOADROW(w1c, Whh1, r2); LOADROW(w1d, Whh1, r3);
  LOADROW(w2a, Wih2, r0); LOADROW(w2b, Wih2, r1); LOADROW(w2c, Wih2, r2); LOADROW(w2d, Wih2, r3);
  LOADROW(w3a, Whh2, r0); LOADROW(w3b, Whh2, r1); LOADROW(w3c, Whh2, r2); LOADROW(w3d, Whh2, r3);

  const float wx0 = Wih1[r0], wx1 = Wih1[r1], wx2 = Wih1[r2], wx3 = Wih1[r3];
  const float bb0 = bih1[r0] + bhh1[r0], bb1 = bih1[r1] + bhh1[r1];
  const float bb2 = bih1[r2] + bhh1[r2], bb3 = bih1[r3] + bhh1[r3];
  const float cb0 = bih2[r0] + bhh2[r0], cb1 = bih2[r1] + bhh2[r1];
  const float cb2 = bih2[r2] + bhh2[r2], cb3 = bih2[r3] + bhh2[r3];
  const float wl = on ? Wlin[uc] : 0.f;
  const float bl = blin[0];

  float c1 = 0.f, c2 = 0.f, fb = 0.f;   // state for (unit u, batch q)

  __syncthreads();

  #pragma unroll 1
  for (int t = 0; t < TTOT; ++t) {
    const int pw = t & 1;
    const int pr = pw ^ 1;

    float xq;
    if (t < TSEEN) xq = xs[t & 255][q];
    else           xq = fb;

    // ========== layer 1: partial dots over k-quarter, 4 rows x 4 batches ==========
    v2f A0 = {0.f,0.f}, A1 = {0.f,0.f}, A2 = {0.f,0.f}, A3 = {0.f,0.f};
    v2f B0 = {0.f,0.f}, B1 = {0.f,0.f}, B2 = {0.f,0.f}, B3 = {0.f,0.f};
    {
      const float4* hp1 = (const float4*)&h1s[pr][kb][0];
      CALL13(L1J)
    }
    QRED(A0); QRED(A1); QRED(A2); QRED(A3);
    QRED(B0); QRED(B1); QRED(B2); QRED(B3);

    float t0 = fmaf(wx0, xq, pick(q, A0, B0) + bb0);
    float t1 = fmaf(wx1, xq, pick(q, A1, B1) + bb1);
    float t2 = fmaf(wx2, xq, pick(q, A2, B2) + bb2);
    float t3 = fmaf(wx3, xq, pick(q, A3, B3) + bb3);

    float h1n;
    cell(t0, t1, t2, t3, c1, h1n);
    if (on) h1s[pw][u][q] = h1n;

    __syncthreads();   // barrier A — the only per-step barrier (seen phase)

    // deferred output: out(t-1) for t-1 in [0, 254]
    if (t >= 1 && t <= TSEEN - 1 && tid < NB) {
      float s = parts[pr][0][tid] + parts[pr][1][tid] +
                parts[pr][2][tid] + parts[pr][3][tid] + bl;
      out[(size_t)(baseb + tid) * TTOT + (t - 1)] = s;
    }

    // ========== layer 2: Wih2 . h1(t)  +  Whh2 . h2(t-1) ==========
    A0 = (v2f){0.f,0.f}; A1 = (v2f){0.f,0.f}; A2 = (v2f){0.f,0.f}; A3 = (v2f){0.f,0.f};
    B0 = (v2f){0.f,0.f}; B1 = (v2f){0.f,0.f}; B2 = (v2f){0.f,0.f}; B3 = (v2f){0.f,0.f};
    {
      const float4* hp2a = (const float4*)&h1s[pw][kb][0];
      const float4* hp2b = (const float4*)&h2s[pr][kb][0];
      CALL13(L2J)
    }
    QRED(A0); QRED(A1); QRED(A2); QRED(A3);
    QRED(B0); QRED(B1); QRED(B2); QRED(B3);

    t0 = pick(q, A0, B0) + cb0;
    t1 = pick(q, A1, B1) + cb1;
    t2 = pick(q, A2, B2) + cb2;
    t3 = pick(q, A3, B3) + cb3;

    float h2n;
    cell(t0, t1, t2, t3, c2, h2n);

    // ---- linear head: butterfly over units within the wave ----
    float pv = wl * h2n;
    pv += __shfl_xor(pv, 4, 64);
    pv += __shfl_xor(pv, 8, 64);
    pv += __shfl_xor(pv, 16, 64);
    pv += __shfl_xor(pv, 32, 64);
    if (lane < 4) parts[pw][wv][lane] = pv;
    if (on) h2s[pw][u][q] = h2n;

    // feedback phase: x(t+1) = out(t); also emit outs 255..271
    if (t >= TSEEN - 1) {
      __syncthreads();   // barrier B (17 steps only)
      fb = parts[pw][0][q] + parts[pw][1][q] +
           parts[pw][2][q] + parts[pw][3][q] + bl;
      if (tid < NB) out[(size_t)(baseb + tid) * TTOT + t] = fb;
    }
  }
}

extern "C" void kernel_launch(void* const* d_in, const int* in_sizes, int n_in,
                              void* d_out, int out_size, void* d_ws, size_t ws_size,
                              hipStream_t stream) {
  (void)in_sizes; (void)n_in; (void)d_ws; (void)ws_size; (void)out_size;
  const float* inp  = (const float*)d_in[0];
  const float* Wih1 = (const float*)d_in[1];
  const float* bih1 = (const float*)d_in[2];
  const float* Whh1 = (const float*)d_in[3];
  const float* bhh1 = (const float*)d_in[4];
  const float* Wih2 = (const float*)d_in[5];
  const float* bih2 = (const float*)d_in[6];
  const float* Whh2 = (const float*)d_in[7];
  const float* bhh2 = (const float*)d_in[8];
  const float* Wlin = (const float*)d_in[9];
  const float* blin = (const float*)d_in[10];
  float* outp = (float*)d_out;

  lstm2_kernel<<<NBLOCKS, THREADS, 0, stream>>>(
      inp, Wih1, bih1, Whh1, bhh1, Wih2, bih2, Whh2, bhh2, Wlin, blin, outp);
}

// Round 5
// 427.032 us; speedup vs baseline: 12.0020x; 12.0020x over previous
//
#include <hip/hip_runtime.h>
#include <math.h>

#define H 51
#define TSEEN 256
#define FUT 16
#define TTOT (TSEEN + FUT)
#define NB 8
#define THREADS 256
#define NBLOCKS (2048 / NB)   // 256 blocks -> 1 per CU

typedef _Float16 f16;
typedef _Float16 f16x8 __attribute__((ext_vector_type(8)));
typedef float f32x4 __attribute__((ext_vector_type(4)));

__device__ __forceinline__ float fast_rcp(float x) { return __builtin_amdgcn_rcpf(x); }
// sigmoid/tanh via v_exp; both saturate cleanly at +-inf (rcp(inf)=0)
__device__ __forceinline__ float sigf(float x) {
  return fast_rcp(1.f + __expf(-x));
}
__device__ __forceinline__ float tanhf_(float x) {
  return fmaf(2.f, fast_rcp(1.f + __expf(-2.f * x)), -1.f);
}

#define MFMA __builtin_amdgcn_mfma_f32_16x16x32_f16

__launch_bounds__(THREADS, 1)
__global__ void lstm2_kernel(const float* __restrict__ inp,
                             const float* __restrict__ Wih1,
                             const float* __restrict__ bih1,
                             const float* __restrict__ Whh1,
                             const float* __restrict__ bhh1,
                             const float* __restrict__ Wih2,
                             const float* __restrict__ bih2,
                             const float* __restrict__ Whh2,
                             const float* __restrict__ bhh2,
                             const float* __restrict__ Wlin,
                             const float* __restrict__ blin,
                             float* __restrict__ out)
{
  // B-operand buffers in MFMA fragment layout:
  // [parity][hi/lo][ktile][lane][j] ; logical (k,n): lane = n + 16*((k&31)>>3), j = k&7
  __shared__ __align__(16) f16 Bh1[2][2][2][64][8];
  __shared__ __align__(16) f16 Bh2[2][2][2][64][8];
  __shared__ __align__(16) float xs[TSEEN][NB];
  __shared__ float parts[2][4][NB];

  const int tid  = threadIdx.x;
  const int wv   = tid >> 6;
  const int lane = tid & 63;
  const int l15  = lane & 15;
  const int g4   = lane >> 4;
  const int baseb = blockIdx.x * NB;

  // ---- zero B buffers (pad slots stay 0 forever) ----
  {
    f16* b1 = &Bh1[0][0][0][0][0];
    f16* b2 = &Bh2[0][0][0][0][0];
    for (int i = tid; i < 2 * 2 * 2 * 64 * 8; i += THREADS) {
      b1[i] = (f16)0.f; b2[i] = (f16)0.f;
    }
  }
  // ---- stage inputs (coalesced per batch row) ----
  for (int i = tid; i < NB * TSEEN; i += THREADS) {
    int b = i >> 8, t = i & 255;
    xs[t][b] = inp[(size_t)(baseb + b) * TSEEN + t];
  }

  // ---- A fragments (f16 weights), virtual row v = 4*(u-13*wv) + gate ----
  // A layout assumed: row = lane&15, k = 32*kt + 8*(lane>>4) + j  (same map used for B)
  f16x8 A1[4][2], A2[4][2], A3[4][2];
  #pragma unroll
  for (int m = 0; m < 4; ++m) {
    const int ulA = 4 * m + (l15 >> 2);
    const int uA  = 13 * wv + ulA;
    const int gA  = l15 & 3;
    const bool vA = (ulA < 13) && (uA < H);
    const int row = gA * H + (vA ? uA : 0);
    #pragma unroll
    for (int kt = 0; kt < 2; ++kt) {
      #pragma unroll
      for (int j = 0; j < 8; ++j) {
        const int k = 32 * kt + 8 * g4 + j;
        float w1 = 0.f, w2 = 0.f, w3 = 0.f;
        if (vA) {
          if (k < H) {
            w1 = Whh1[row * H + k];
            w2 = Wih2[row * H + k];
            w3 = Whh2[row * H + k];
          } else if (k == H) {
            w1 = Wih1[row];        // x folded in as k-slot 51 (layer 1 only)
          }
        }
        A1[m][kt][j] = (f16)w1;
        A2[m][kt][j] = (f16)w2;
        A3[m][kt][j] = (f16)w3;
      }
    }
  }

  // ---- bias C-in fragments, head weights, cell state (C layout: unit=4m+g4, gate=reg) ----
  f32x4 bias1[4], bias2[4];
  float wlv[4], c1[4], c2[4];
  bool vc[4]; int cu[4];
  #pragma unroll
  for (int m = 0; m < 4; ++m) {
    const int ulC = 4 * m + g4;
    const int u   = 13 * wv + ulC;
    const bool v  = (ulC < 13) && (u < H);
    vc[m] = v; cu[m] = u;
    #pragma unroll
    for (int r = 0; r < 4; ++r) {
      const int rr = r * H + (v ? u : 0);
      bias1[m][r] = v ? (bih1[rr] + bhh1[rr]) : 0.f;
      bias2[m][r] = v ? (bih2[rr] + bhh2[rr]) : 0.f;
    }
    wlv[m] = v ? Wlin[u] : 0.f;
    c1[m] = 0.f; c2[m] = 0.f;
  }
  const float bl = blin[0];

  __syncthreads();
  // x(0) into stale-parity h1 buffer, slot k=51 (kt=1,k'=19 -> lane n+32, j=3)
  if (tid < NB) {
    float x0 = xs[0][tid];
    f16 xh = (f16)x0;
    Bh1[1][0][1][tid + 32][3] = xh;
    Bh1[1][1][1][tid + 32][3] = (f16)(x0 - (float)xh);
  }
  __syncthreads();

  #pragma unroll 1
  for (int t = 0; t < TTOT; ++t) {
    const int pw = t & 1, pr = pw ^ 1;

    // ---- B frags: h1(t-1)+x (layer1) and h2(t-1) (layer2-hh), hi+lo ----
    const f16x8 b1h0 = *(const f16x8*)&Bh1[pr][0][0][lane][0];
    const f16x8 b1h1 = *(const f16x8*)&Bh1[pr][0][1][lane][0];
    const f16x8 b1l0 = *(const f16x8*)&Bh1[pr][1][0][lane][0];
    const f16x8 b1l1 = *(const f16x8*)&Bh1[pr][1][1][lane][0];
    const f16x8 b2h0 = *(const f16x8*)&Bh2[pr][0][0][lane][0];
    const f16x8 b2h1 = *(const f16x8*)&Bh2[pr][0][1][lane][0];
    const f16x8 b2l0 = *(const f16x8*)&Bh2[pr][1][0][lane][0];
    const f16x8 b2l1 = *(const f16x8*)&Bh2[pr][1][1][lane][0];

    f32x4 ac1[4], ac2[4];
    #pragma unroll
    for (int m = 0; m < 4; ++m) {
      ac1[m] = MFMA(A1[m][0], b1h0, bias1[m], 0, 0, 0);
      ac1[m] = MFMA(A1[m][1], b1h1, ac1[m], 0, 0, 0);
      ac1[m] = MFMA(A1[m][0], b1l0, ac1[m], 0, 0, 0);
      ac1[m] = MFMA(A1[m][1], b1l1, ac1[m], 0, 0, 0);
      ac2[m] = MFMA(A3[m][0], b2h0, bias2[m], 0, 0, 0);
      ac2[m] = MFMA(A3[m][1], b2h1, ac2[m], 0, 0, 0);
      ac2[m] = MFMA(A3[m][0], b2l0, ac2[m], 0, 0, 0);
      ac2[m] = MFMA(A3[m][1], b2l1, ac2[m], 0, 0, 0);
    }

    // ---- layer-1 cell update (per-lane: unit cu[m], batch l15, gates = acc regs) ----
    #pragma unroll
    for (int m = 0; m < 4; ++m) {
      float iv = sigf(ac1[m][0]);
      float fv = sigf(ac1[m][1]);
      float gv = tanhf_(ac1[m][2]);
      float ov = sigf(ac1[m][3]);
      c1[m] = fmaf(fv, c1[m], iv * gv);
      float h = ov * tanhf_(c1[m]);
      if (vc[m] && l15 < NB) {
        const int u = cu[m];
        f16 hh = (f16)h;
        Bh1[pw][0][u >> 5][l15 + 16 * ((u >> 3) & 3)][u & 7] = hh;
        Bh1[pw][1][u >> 5][l15 + 16 * ((u >> 3) & 3)][u & 7] = (f16)(h - (float)hh);
      }
    }
    __syncthreads();   // barrier A

    // deferred output: out(t-1) for t-1 in [0, 254]
    if (t >= 1 && t < TSEEN && tid < NB) {
      float s = parts[pr][0][tid] + parts[pr][1][tid] +
                parts[pr][2][tid] + parts[pr][3][tid] + bl;
      out[(size_t)(baseb + tid) * TTOT + (t - 1)] = s;
    }

    // ---- layer-2 ih: fresh h1(t) frags (slot 51 zero-weighted in A2) ----
    const f16x8 f1h0 = *(const f16x8*)&Bh1[pw][0][0][lane][0];
    const f16x8 f1h1 = *(const f16x8*)&Bh1[pw][0][1][lane][0];
    const f16x8 f1l0 = *(const f16x8*)&Bh1[pw][1][0][lane][0];
    const f16x8 f1l1 = *(const f16x8*)&Bh1[pw][1][1][lane][0];
    #pragma unroll
    for (int m = 0; m < 4; ++m) {
      ac2[m] = MFMA(A2[m][0], f1h0, ac2[m], 0, 0, 0);
      ac2[m] = MFMA(A2[m][1], f1h1, ac2[m], 0, 0, 0);
      ac2[m] = MFMA(A2[m][0], f1l0, ac2[m], 0, 0, 0);
      ac2[m] = MFMA(A2[m][1], f1l1, ac2[m], 0, 0, 0);
    }

    // ---- layer-2 cell + head partial ----
    float pv = 0.f;
    #pragma unroll
    for (int m = 0; m < 4; ++m) {
      float iv = sigf(ac2[m][0]);
      float fv = sigf(ac2[m][1]);
      float gv = tanhf_(ac2[m][2]);
      float ov = sigf(ac2[m][3]);
      c2[m] = fmaf(fv, c2[m], iv * gv);
      float h = ov * tanhf_(c2[m]);
      pv = fmaf(wlv[m], h, pv);
      if (vc[m] && l15 < NB) {
        const int u = cu[m];
        f16 hh = (f16)h;
        Bh2[pw][0][u >> 5][l15 + 16 * ((u >> 3) & 3)][u & 7] = hh;
        Bh2[pw][1][u >> 5][l15 + 16 * ((u >> 3) & 3)][u & 7] = (f16)(h - (float)hh);
      }
    }
    pv += __shfl_xor(pv, 16, 64);
    pv += __shfl_xor(pv, 32, 64);
    if (g4 == 0 && l15 < NB) parts[pw][wv][l15] = pv;

    if (t < TSEEN - 1) {
      // x(t+1) from input into Bh1[pw] slot 51 (benign byte-race: stale x * zero col)
      if (tid < NB) {
        float xn = xs[t + 1][tid];
        f16 xh = (f16)xn;
        Bh1[pw][0][1][tid + 32][3] = xh;
        Bh1[pw][1][1][tid + 32][3] = (f16)(xn - (float)xh);
      }
      __syncthreads();   // barrier B
    } else {
      __syncthreads();   // barrier B (feedback: need out(t) now)
      if (tid < NB) {
        float fbv = parts[pw][0][tid] + parts[pw][1][tid] +
                    parts[pw][2][tid] + parts[pw][3][tid] + bl;
        out[(size_t)(baseb + tid) * TTOT + t] = fbv;
        if (t < TTOT - 1) {
          f16 xh = (f16)fbv;
          Bh1[pw][0][1][tid + 32][3] = xh;
          Bh1[pw][1][1][tid + 32][3] = (f16)(fbv - (float)xh);
        }
      }
      __syncthreads();   // barrier C
    }
  }
}

extern "C" void kernel_launch(void* const* d_in, const int* in_sizes, int n_in,
                              void* d_out, int out_size, void* d_ws, size_t ws_size,
                              hipStream_t stream) {
  (void)in_sizes; (void)n_in; (void)d_ws; (void)ws_size; (void)out_size;
  const float* inp  = (const float*)d_in[0];
  const float* Wih1 = (const float*)d_in[1];
  const float* bih1 = (const float*)d_in[2];
  const float* Whh1 = (const float*)d_in[3];
  const float* bhh1 = (const float*)d_in[4];
  const float* Wih2 = (const float*)d_in[5];
  const float* bih2 = (const float*)d_in[6];
  const float* Whh2 = (const float*)d_in[7];
  const float* bhh2 = (const float*)d_in[8];
  const float* Wlin = (const float*)d_in[9];
  const float* blin = (const float*)d_in[10];
  float* outp = (float*)d_out;

  lstm2_kernel<<<NBLOCKS, THREADS, 0, stream>>>(
      inp, Wih1, bih1, Whh1, bhh1, Wih2, bih2, Whh2, bhh2, Wlin, blin, outp);
}

// Round 6
// 300.556 us; speedup vs baseline: 17.0525x; 1.4208x over previous
//
#include <hip/hip_runtime.h>
#include <math.h>

#define H 51
#define TSEEN 256
#define FUT 16
#define TTOT (TSEEN + FUT)
#define NB 8
#define THREADS 512
#define NWAVE 8
#define UPW 7                 // units per wave (8*7=56 >= 51)
#define NBLOCKS (2048 / NB)   // 256 blocks -> 1/CU, 8 waves = 2 waves/SIMD

typedef _Float16 f16;
typedef _Float16 f16x8 __attribute__((ext_vector_type(8)));
typedef float f32x4 __attribute__((ext_vector_type(4)));

__device__ __forceinline__ float fast_rcp(float x) { return __builtin_amdgcn_rcpf(x); }
// sigmoid/tanh via v_exp; both saturate cleanly (rcp(inf)=0)
__device__ __forceinline__ float sigf(float x) {
  return fast_rcp(1.f + __expf(-x));
}
__device__ __forceinline__ float tanhf_(float x) {
  return fmaf(2.f, fast_rcp(1.f + __expf(-2.f * x)), -1.f);
}

#define MFMA __builtin_amdgcn_mfma_f32_16x16x32_f16

__launch_bounds__(THREADS, 2)
__global__ void lstm2_kernel(const float* __restrict__ inp,
                             const float* __restrict__ Wih1,
                             const float* __restrict__ bih1,
                             const float* __restrict__ Whh1,
                             const float* __restrict__ bhh1,
                             const float* __restrict__ Wih2,
                             const float* __restrict__ bih2,
                             const float* __restrict__ Whh2,
                             const float* __restrict__ bhh2,
                             const float* __restrict__ Wlin,
                             const float* __restrict__ blin,
                             float* __restrict__ out)
{
  // B-operand buffers in MFMA fragment layout:
  // [parity][hi/lo][ktile][lane][j]; logical (k,n): lane = n + 16*((k&31)>>3), j = k&7
  __shared__ __align__(16) f16 Bh1[2][2][2][64][8];
  __shared__ __align__(16) f16 Bh2[2][2][2][64][8];
  __shared__ __align__(16) float xs[TSEEN][NB];
  __shared__ float parts[2][NWAVE][NB];

  const int tid  = threadIdx.x;
  const int wv   = tid >> 6;
  const int lane = tid & 63;
  const int l15  = lane & 15;
  const int g4   = lane >> 4;
  const int bq   = l15 & 7;            // this lane's batch for the cell phase
  const bool mhi = (l15 & 8) != 0;     // takes the m=1 accumulator via xor-8
  const int baseb = blockIdx.x * NB;

  // ---- zero B buffers (pad slots stay 0 forever) ----
  {
    f16* b1 = &Bh1[0][0][0][0][0];
    f16* b2 = &Bh2[0][0][0][0][0];
    for (int i = tid; i < 2 * 2 * 2 * 64 * 8; i += THREADS) {
      b1[i] = (f16)0.f; b2[i] = (f16)0.f;
    }
  }
  // ---- stage inputs (coalesced per batch row) ----
  for (int i = tid; i < NB * TSEEN; i += THREADS) {
    int b = i >> 8, t = i & 255;
    xs[t][b] = inp[(size_t)(baseb + b) * TSEEN + t];
  }
  if (tid < 2 * NWAVE * NB) (&parts[0][0][0])[tid] = 0.f;

  // ---- A fragments (f16), virtual row v = 4*unit_slot + gate; 2 M-tiles/wave ----
  f16x8 A1[2][2], A2[2][2], A3[2][2];
  #pragma unroll
  for (int m = 0; m < 2; ++m) {
    const int slotA = 4 * m + (l15 >> 2);
    const int uA = UPW * wv + slotA;
    const int gA = l15 & 3;
    const bool vA = (slotA < UPW) && (uA < H);
    const int row = gA * H + (vA ? uA : 0);
    #pragma unroll
    for (int kt = 0; kt < 2; ++kt) {
      #pragma unroll
      for (int j = 0; j < 8; ++j) {
        const int k = 32 * kt + 8 * g4 + j;
        float w1 = 0.f, w2 = 0.f, w3 = 0.f;
        if (vA) {
          if (k < H) {
            w1 = Whh1[row * H + k];
            w2 = Wih2[row * H + k];
            w3 = Whh2[row * H + k];
          } else if (k == H) {
            w1 = Wih1[row];        // x folded in as k-slot 51 (layer 1 only)
          }
        }
        A1[m][kt][j] = (f16)w1;
        A2[m][kt][j] = (f16)w2;
        A3[m][kt][j] = (f16)w3;
      }
    }
  }

  // ---- bias C-in fragments (C layout: unit_slot = 4m+g4, gate = reg) ----
  f32x4 bias1[2], bias2[2];
  #pragma unroll
  for (int m = 0; m < 2; ++m) {
    const int ulC = 4 * m + g4;
    const int u = UPW * wv + ulC;
    const bool v = (ulC < UPW) && (u < H);
    #pragma unroll
    for (int r = 0; r < 4; ++r) {
      const int rr = r * H + (v ? u : 0);
      bias1[m][r] = v ? (bih1[rr] + bhh1[rr]) : 0.f;
      bias2[m][r] = v ? (bih2[rr] + bhh2[rr]) : 0.f;
    }
  }

  // ---- this lane's cell: unit slot (mhi? 4:0)+g4, batch bq ----
  const int slotC = (mhi ? 4 : 0) + g4;
  const int uC0 = UPW * wv + slotC;
  const bool vC = (slotC < UPW) && (uC0 < H);
  const int uC = vC ? uC0 : 0;
  const float wl = vC ? Wlin[uC] : 0.f;
  const float bl = blin[0];
  const int wkt = uC >> 5;                    // h-frag write address for (uC,bq)
  const int wln = bq + 16 * ((uC >> 3) & 3);
  const int wj  = uC & 7;

  float c1 = 0.f, c2 = 0.f;

  __syncthreads();
  // x(0) into stale-parity h1 buffer, k-slot 51 (kt=1 -> lane n+32, j=3)
  if (tid < NB) {
    float x0 = xs[0][tid];
    f16 xh = (f16)x0;
    Bh1[1][0][1][tid + 32][3] = xh;
    Bh1[1][1][1][tid + 32][3] = (f16)(x0 - (float)xh);
  }
  __syncthreads();

  #pragma unroll 1
  for (int t = 0; t < TTOT; ++t) {
    const int pw = t & 1, pr = pw ^ 1;

    // ---- B frags: h1(t-1)+x (layer1) and h2(t-1) (layer2-hh), hi+lo ----
    const f16x8 b1h0 = *(const f16x8*)&Bh1[pr][0][0][lane][0];
    const f16x8 b1h1 = *(const f16x8*)&Bh1[pr][0][1][lane][0];
    const f16x8 b1l0 = *(const f16x8*)&Bh1[pr][1][0][lane][0];
    const f16x8 b1l1 = *(const f16x8*)&Bh1[pr][1][1][lane][0];
    const f16x8 b2h0 = *(const f16x8*)&Bh2[pr][0][0][lane][0];
    const f16x8 b2h1 = *(const f16x8*)&Bh2[pr][0][1][lane][0];
    const f16x8 b2l0 = *(const f16x8*)&Bh2[pr][1][0][lane][0];
    const f16x8 b2l1 = *(const f16x8*)&Bh2[pr][1][1][lane][0];

    f32x4 ac1[2], ac2[2];
    #pragma unroll
    for (int m = 0; m < 2; ++m) {
      ac1[m] = MFMA(A1[m][0], b1h0, bias1[m], 0, 0, 0);
      ac1[m] = MFMA(A1[m][1], b1h1, ac1[m], 0, 0, 0);
      ac1[m] = MFMA(A1[m][0], b1l0, ac1[m], 0, 0, 0);
      ac1[m] = MFMA(A1[m][1], b1l1, ac1[m], 0, 0, 0);
      ac2[m] = MFMA(A3[m][0], b2h0, bias2[m], 0, 0, 0);
      ac2[m] = MFMA(A3[m][1], b2h1, ac2[m], 0, 0, 0);
      ac2[m] = MFMA(A3[m][0], b2l0, ac2[m], 0, 0, 0);
      ac2[m] = MFMA(A3[m][1], b2l1, ac2[m], 0, 0, 0);
    }

    // ---- layer-1: xor-8 exchange -> 1 cell per lane ----
    float q0, q1, q2, q3;
    {
      float e0 = __shfl_xor(ac1[1][0], 8, 64);
      float e1 = __shfl_xor(ac1[1][1], 8, 64);
      float e2 = __shfl_xor(ac1[1][2], 8, 64);
      float e3 = __shfl_xor(ac1[1][3], 8, 64);
      q0 = mhi ? e0 : ac1[0][0];
      q1 = mhi ? e1 : ac1[0][1];
      q2 = mhi ? e2 : ac1[0][2];
      q3 = mhi ? e3 : ac1[0][3];
    }
    {
      float iv = sigf(q0), fv = sigf(q1);
      float gv = tanhf_(q2), ov = sigf(q3);
      c1 = fmaf(fv, c1, iv * gv);
      float h1n = ov * tanhf_(c1);
      if (vC) {
        f16 hh = (f16)h1n;
        Bh1[pw][0][wkt][wln][wj] = hh;
        Bh1[pw][1][wkt][wln][wj] = (f16)(h1n - (float)hh);
      }
    }
    __syncthreads();   // barrier A

    // deferred output: out(t-1) for t-1 in [0, 254]
    if (t >= 1 && t < TSEEN && tid < NB) {
      float s = bl;
      #pragma unroll
      for (int w = 0; w < NWAVE; ++w) s += parts[pr][w][tid];
      out[(size_t)(baseb + tid) * TTOT + (t - 1)] = s;
    }

    // ---- layer-2 ih: fresh h1(t) frags (k-slot 51 zero-weighted in A2) ----
    const f16x8 f1h0 = *(const f16x8*)&Bh1[pw][0][0][lane][0];
    const f16x8 f1h1 = *(const f16x8*)&Bh1[pw][0][1][lane][0];
    const f16x8 f1l0 = *(const f16x8*)&Bh1[pw][1][0][lane][0];
    const f16x8 f1l1 = *(const f16x8*)&Bh1[pw][1][1][lane][0];
    #pragma unroll
    for (int m = 0; m < 2; ++m) {
      ac2[m] = MFMA(A2[m][0], f1h0, ac2[m], 0, 0, 0);
      ac2[m] = MFMA(A2[m][1], f1h1, ac2[m], 0, 0, 0);
      ac2[m] = MFMA(A2[m][0], f1l0, ac2[m], 0, 0, 0);
      ac2[m] = MFMA(A2[m][1], f1l1, ac2[m], 0, 0, 0);
    }

    // ---- layer-2: exchange + cell + head ----
    {
      float e0 = __shfl_xor(ac2[1][0], 8, 64);
      float e1 = __shfl_xor(ac2[1][1], 8, 64);
      float e2 = __shfl_xor(ac2[1][2], 8, 64);
      float e3 = __shfl_xor(ac2[1][3], 8, 64);
      q0 = mhi ? e0 : ac2[0][0];
      q1 = mhi ? e1 : ac2[0][1];
      q2 = mhi ? e2 : ac2[0][2];
      q3 = mhi ? e3 : ac2[0][3];
    }
    float pv;
    {
      float iv = sigf(q0), fv = sigf(q1);
      float gv = tanhf_(q2), ov = sigf(q3);
      c2 = fmaf(fv, c2, iv * gv);
      float h2n = ov * tanhf_(c2);
      pv = wl * h2n;
      if (vC) {
        f16 hh = (f16)h2n;
        Bh2[pw][0][wkt][wln][wj] = hh;
        Bh2[pw][1][wkt][wln][wj] = (f16)(h2n - (float)hh);
      }
    }
    // butterfly over unit slots: xor 8 (m-half), 16/32 (g4)
    pv += __shfl_xor(pv, 8, 64);
    pv += __shfl_xor(pv, 16, 64);
    pv += __shfl_xor(pv, 32, 64);
    if (lane < NB) parts[pw][wv][lane] = pv;

    if (t < TSEEN - 1) {
      // x(t+1) into Bh1[pw] k-slot 51 (benign race: A2 column 51 is zero)
      if (tid < NB) {
        float xn = xs[t + 1][tid];
        f16 xh = (f16)xn;
        Bh1[pw][0][1][tid + 32][3] = xh;
        Bh1[pw][1][1][tid + 32][3] = (f16)(xn - (float)xh);
      }
      __syncthreads();   // barrier B
    } else {
      __syncthreads();   // barrier B (feedback: need out(t) now)
      if (tid < NB) {
        float fbv = bl;
        #pragma unroll
        for (int w = 0; w < NWAVE; ++w) fbv += parts[pw][w][tid];
        out[(size_t)(baseb + tid) * TTOT + t] = fbv;
        if (t < TTOT - 1) {
          f16 xh = (f16)fbv;
          Bh1[pw][0][1][tid + 32][3] = xh;
          Bh1[pw][1][1][tid + 32][3] = (f16)(fbv - (float)xh);
        }
      }
      __syncthreads();   // barrier C
    }
  }
}

extern "C" void kernel_launch(void* const* d_in, const int* in_sizes, int n_in,
                              void* d_out, int out_size, void* d_ws, size_t ws_size,
                              hipStream_t stream) {
  (void)in_sizes; (void)n_in; (void)d_ws; (void)ws_size; (void)out_size;
  const float* inp  = (const float*)d_in[0];
  const float* Wih1 = (const float*)d_in[1];
  const float* bih1 = (const float*)d_in[2];
  const float* Whh1 = (const float*)d_in[3];
  const float* bhh1 = (const float*)d_in[4];
  const float* Wih2 = (const float*)d_in[5];
  const float* bih2 = (const float*)d_in[6];
  const float* Whh2 = (const float*)d_in[7];
  const float* bhh2 = (const float*)d_in[8];
  const float* Wlin = (const float*)d_in[9];
  const float* blin = (const float*)d_in[10];
  float* outp = (float*)d_out;

  lstm2_kernel<<<NBLOCKS, THREADS, 0, stream>>>(
      inp, Wih1, bih1, Whh1, bhh1, Wih2, bih2, Whh2, bhh2, Wlin, blin, outp);
}